// Round 6
// baseline (250.475 us; speedup 1.0000x reference)
//
#include <hip/hip_runtime.h>

#define D_IN  128
#define D_HID 128
#define D_OUT 64
#define NBMAX 512      // max buckets (N <= 65536)
#define CHUNK 4096     // edges per k_bucket block
#define BM 128
#define BK 32

// ---------------------------------------------------------------- bucket scatter
// Counting-sort pass 1: scatter edges into 128-node dst-buckets (int2 src,dst)
// and src values into 128-node src-buckets. LDS-aggregated reservations.
__launch_bounds__(256)
__global__ void k_bucket(const int* __restrict__ src, const int* __restrict__ dst,
                         int E, int NB, int cap,
                         int* __restrict__ cntD, int* __restrict__ cntS,
                         int2* __restrict__ storeD, int* __restrict__ storeS) {
    __shared__ int lcD[NBMAX], lcS[NBMAX];
    __shared__ int lbD[NBMAX], lbS[NBMAX];
    const int t = threadIdx.x;
    const int e0 = blockIdx.x * CHUNK;
    const int e1 = min(e0 + CHUNK, E);

    for (int i = t; i < NB; i += 256) { lcD[i] = 0; lcS[i] = 0; }
    __syncthreads();
    for (int i = e0 + t; i < e1; i += 256) {
        atomicAdd(&lcD[dst[i] >> 7], 1);
        atomicAdd(&lcS[src[i] >> 7], 1);
    }
    __syncthreads();
    for (int i = t; i < NB; i += 256) {
        lbD[i] = lcD[i] ? atomicAdd(&cntD[i], lcD[i]) : 0;
        lbS[i] = lcS[i] ? atomicAdd(&cntS[i], lcS[i]) : 0;
        lcD[i] = 0; lcS[i] = 0;
    }
    __syncthreads();
    for (int i = e0 + t; i < e1; i += 256) {
        const int s = src[i], d = dst[i];
        const int bd = d >> 7;
        const int pd = lbD[bd] + atomicAdd(&lcD[bd], 1);
        storeD[(long long)bd * cap + pd] = make_int2(s, d);
        const int bs = s >> 7;
        const int ps = lbS[bs] + atomicAdd(&lcS[bs], 1);
        storeS[(long long)bs * cap + ps] = s;
    }
}

// ---------------------------------------------------------------- bucket scan
__launch_bounds__(512)
__global__ void k_scan512(const int* __restrict__ cntD, int* __restrict__ coarse_off,
                          int NB, int* __restrict__ rowptr_last, int E) {
    __shared__ int sh[512];
    const int t = threadIdx.x;
    const int v = (t < NB) ? cntD[t] : 0;
    sh[t] = v; __syncthreads();
    int inc = v;
    for (int off = 1; off < 512; off <<= 1) {
        int o = (t >= off) ? sh[t - off] : 0;
        __syncthreads();
        inc += o; sh[t] = inc;
        __syncthreads();
    }
    if (t < NB) coarse_off[t] = inc - v;
    if (t == 0) *rowptr_last = E;
}

// ---------------------------------------------------------------- finalize
// Per dst-bucket: 128-bin LDS histogram + scan -> rowptr, inv_in, csr_src.
// Then per src-bucket: histogram -> inv_out.
__launch_bounds__(256)
__global__ void k_fin(const int2* __restrict__ storeD, const int* __restrict__ storeS,
                      const int* __restrict__ cntD, const int* __restrict__ cntS,
                      const int* __restrict__ coarse_off, int cap, int N,
                      int* __restrict__ rowptr, float* __restrict__ inv_in,
                      float* __restrict__ inv_out, int* __restrict__ csr_src) {
    __shared__ int fh[128];
    __shared__ int sc[128];
    __shared__ int cur[128];
    const int b = blockIdx.x, t = threadIdx.x;
    const long long sb = (long long)b * cap;

    // ---- dst side: rowptr / inv_in / csr_src
    const int cnt  = cntD[b];
    const int base = coarse_off[b];
    if (t < 128) fh[t] = 0;
    __syncthreads();
    for (int i = t; i < cnt; i += 256) atomicAdd(&fh[storeD[sb + i].y & 127], 1);
    __syncthreads();
    if (t < 128) sc[t] = fh[t];
    __syncthreads();
    int inc = (t < 128) ? sc[t] : 0;
    for (int off = 1; off < 128; off <<= 1) {
        int o = (t >= off && t < 128) ? sc[t - off] : 0;
        __syncthreads();
        if (t < 128) { inc += o; sc[t] = inc; }
        __syncthreads();
    }
    if (t < 128) {
        const int excl = inc - fh[t];
        cur[t] = excl;
        const int node = (b << 7) + t;
        if (node < N) {
            rowptr[node] = base + excl;
            inv_in[node] = rsqrtf((float)max(fh[t], 1));
        }
    }
    __syncthreads();
    for (int i = t; i < cnt; i += 256) {
        const int2 e = storeD[sb + i];
        const int pos = atomicAdd(&cur[e.y & 127], 1);
        csr_src[base + pos] = e.x;
    }

    // ---- src side: inv_out
    __syncthreads();
    if (t < 128) fh[t] = 0;
    __syncthreads();
    const int cnts = cntS[b];
    for (int i = t; i < cnts; i += 256) atomicAdd(&fh[storeS[sb + i] & 127], 1);
    __syncthreads();
    if (t < 128) {
        const int node = (b << 7) + t;
        if (node < N) inv_out[node] = rsqrtf((float)max(fh[t], 1));
    }
}

// ---------------------------------------------------------------- register-blocked SGEMM
// Y[i][j] = sum_k X[i][k] * scale_i * W[k][j]   (scale optional)
// Block tile BM=128 x BN, K-chunks of BK=32. 256 threads = 16x16.
// Thread tile: 8 rows x (BN/16) cols. As is staged TRANSPOSED: As[k][row].
template<int BN>
__launch_bounds__(256, 4)
__global__ void k_gemm2(const float* __restrict__ X, const float* __restrict__ W,
                        const float* __restrict__ scale, float* __restrict__ Y, int N) {
    constexpr int TN = BN / 16;            // 8 (BN=128) or 4 (BN=64)
    __shared__ float As[BK][BM + 4];       // stride 132: float4-aligned, broadcast reads
    __shared__ float Bs[BK][BN];

    const int t  = threadIdx.x;
    const int tx = t & 15;
    const int ty = t >> 4;
    const int row0 = blockIdx.x * BM;

    const int xr = t >> 3;                 // 0..31 (staging row within pass)
    const int xc = (t & 7) * 4;            // 0..28 (staging k-col)

    float acc[8][TN];
#pragma unroll
    for (int m = 0; m < 8; ++m)
#pragma unroll
        for (int n = 0; n < TN; ++n) acc[m][n] = 0.0f;

    for (int kk = 0; kk < D_IN; kk += BK) {
        __syncthreads();                   // protect previous-iteration reads
        // stage X tile (BM x BK) transposed, 4 passes of 32 rows
#pragma unroll
        for (int p = 0; p < 4; ++p) {
            const int r  = p * 32 + xr;
            const int gr = row0 + r;
            float4 v = make_float4(0.f, 0.f, 0.f, 0.f);
            if (gr < N) {
                v = *(const float4*)(X + (long long)gr * D_IN + kk + xc);
                if (scale) { const float s = scale[gr]; v.x *= s; v.y *= s; v.z *= s; v.w *= s; }
            }
            As[xc + 0][r] = v.x;
            As[xc + 1][r] = v.y;
            As[xc + 2][r] = v.z;
            As[xc + 3][r] = v.w;
        }
        // stage W tile (BK x BN), direct float4
#pragma unroll
        for (int p = 0; p < BN / 32; ++p) {
            const int flat = p * 256 + t;              // float4 index
            const int kr = flat / (BN / 4);
            const int jc = (flat % (BN / 4)) * 4;
            *(float4*)&Bs[kr][jc] = *(const float4*)(W + (long long)(kk + kr) * BN + jc);
        }
        __syncthreads();

#pragma unroll
        for (int k = 0; k < BK; ++k) {
            const float4 A0 = *(const float4*)&As[k][ty * 4];
            const float4 A1 = *(const float4*)&As[k][64 + ty * 4];
            const float a[8] = {A0.x, A0.y, A0.z, A0.w, A1.x, A1.y, A1.z, A1.w};
            float bf[TN];
            const float4 B0 = *(const float4*)&Bs[k][tx * 4];
            bf[0] = B0.x; bf[1] = B0.y; bf[2] = B0.z; bf[3] = B0.w;
            if (BN == 128) {
                const float4 B1 = *(const float4*)&Bs[k][64 + tx * 4];
                bf[4] = B1.x; bf[5] = B1.y; bf[6] = B1.z; bf[7] = B1.w;
            }
#pragma unroll
            for (int m = 0; m < 8; ++m)
#pragma unroll
                for (int n = 0; n < TN; ++n)
                    acc[m][n] += a[m] * bf[n];
        }
    }

    // epilogue: rows {ty*4+u, 64+ty*4+u}, cols {tx*4.., (+64..)}
#pragma unroll
    for (int m = 0; m < 8; ++m) {
        const int r  = (m < 4) ? (ty * 4 + m) : (64 + ty * 4 + (m - 4));
        const int gr = row0 + r;
        if (gr < N) {
            *(float4*)(Y + (long long)gr * BN + tx * 4) =
                make_float4(acc[m][0], acc[m][1], acc[m][2], acc[m][3]);
            if (BN == 128)
                *(float4*)(Y + (long long)gr * BN + 64 + tx * 4) =
                    make_float4(acc[m][4], acc[m][5], acc[m][6], acc[m][7]);
        }
    }
}

// ---------------------------------------------------------------- CSR gather
// One wave per destination node; EPW edges in flight (float4 per lane):
//   D=128: 2 edges x 32 lanes;  D=64: 4 edges x 16 lanes.
template<int D, bool RELU>
__launch_bounds__(256)
__global__ void k_gather(const int* __restrict__ rowptr, const int* __restrict__ csr_src,
                         const float* __restrict__ Y, const float* __restrict__ inv_in,
                         const float* __restrict__ inv_out, const float* __restrict__ b,
                         float* __restrict__ out, int N) {
    const int wid  = (int)((blockIdx.x * 256u + threadIdx.x) >> 6);
    const int lane = threadIdx.x & 63;
    if (wid >= N) return;

    const int start = rowptr[wid];
    const int end   = rowptr[wid + 1];

    constexpr int LPE = D / 4;            // lanes per edge (32 or 16)
    constexpr int EPW = 64 / LPE;         // edges in flight  (2 or 4)
    const int grp  = lane / LPE;          // 0..EPW-1
    const int col4 = (lane % LPE) * 4;

    float4 acc = make_float4(0.f, 0.f, 0.f, 0.f);
    for (int k = start; k < end; k += 64) {
        const int idx = k + lane;
        const int sv  = (idx < end) ? csr_src[idx] : 0;
        const int cnt = min(64, end - k);
        for (int j = 0; j < cnt; j += EPW) {
            const int jj = j + grp;
            const int s  = __shfl(sv, jj);
            if (jj < cnt) {
                float4 v = *(const float4*)(Y + (long long)s * D + col4);
                acc.x += v.x; acc.y += v.y; acc.z += v.z; acc.w += v.w;
            }
        }
    }

    // combine the EPW edge groups (they hold the same columns)
    acc.x += __shfl_down(acc.x, 32); acc.y += __shfl_down(acc.y, 32);
    acc.z += __shfl_down(acc.z, 32); acc.w += __shfl_down(acc.w, 32);
    if (EPW == 4) {
        acc.x += __shfl_down(acc.x, 16); acc.y += __shfl_down(acc.y, 16);
        acc.z += __shfl_down(acc.z, 16); acc.w += __shfl_down(acc.w, 16);
    }

    if (lane < LPE) {
        const float ii = inv_in[wid];
        const float4 bb = *(const float4*)(b + col4);
        float4 r;
        r.x = acc.x * ii + bb.x;
        r.y = acc.y * ii + bb.y;
        r.z = acc.z * ii + bb.z;
        r.w = acc.w * ii + bb.w;
        if (RELU) {
            const float io = inv_out[wid];
            r.x = fmaxf(r.x, 0.0f) * io;
            r.y = fmaxf(r.y, 0.0f) * io;
            r.z = fmaxf(r.z, 0.0f) * io;
            r.w = fmaxf(r.w, 0.0f) * io;
        }
        *(float4*)(out + (long long)wid * D + col4) = r;
    }
}

// ---------------------------------------------------------------- launch
extern "C" void kernel_launch(void* const* d_in, const int* in_sizes, int n_in,
                              void* d_out, int out_size, void* d_ws, size_t ws_size,
                              hipStream_t stream) {
    const int*   src = (const int*)d_in[0];
    const int*   dst = (const int*)d_in[1];
    const float* x   = (const float*)d_in[2];
    const float* W1  = (const float*)d_in[3];
    const float* b1  = (const float*)d_in[4];
    const float* W2  = (const float*)d_in[5];
    const float* b2  = (const float*)d_in[6];
    float* out = (float*)d_out;

    const int E  = in_sizes[0];
    const int N  = in_sizes[2] / D_IN;
    const int NB = (N + 127) >> 7;                 // 128-node buckets (<= NBMAX)
    const int mean = E / NB;
    const int cap  = mean + mean / 4 + 128;        // generous multinomial margin

    char* ws = (char*)d_ws;
    size_t off = 0;
    auto alloc = [&](size_t bytes) -> void* {
        void* p = ws + off;
        off += (bytes + 255) & ~(size_t)255;
        return p;
    };
    float* inv_out  = (float*)alloc((size_t)N * 4);
    float* inv_in   = (float*)alloc((size_t)N * 4);
    int*   rowptr   = (int*)alloc((size_t)(N + 1) * 4);
    int*   cntD     = (int*)alloc((size_t)NB * 4);
    int*   cntS     = (int*)alloc((size_t)NB * 4);
    int*   coarse   = (int*)alloc((size_t)NB * 4);
    int2*  storeD   = (int2*)alloc((size_t)NB * cap * 8);
    int*   storeS   = (int*)alloc((size_t)NB * cap * 4);
    int*   csr_src  = (int*)alloc((size_t)E * 4);
    float* Y1       = (float*)alloc((size_t)N * D_HID * 4);
    float* H        = (float*)alloc((size_t)N * D_HID * 4);
    float* Y2       = (float*)alloc((size_t)N * D_OUT * 4);
    (void)ws_size; (void)n_in; (void)out_size;

    hipMemsetAsync(cntD, 0, (size_t)NB * 4, stream);
    hipMemsetAsync(cntS, 0, (size_t)NB * 4, stream);

    // CSR build + degree norms (counting sort, LDS-aggregated)
    k_bucket<<<(E + CHUNK - 1) / CHUNK, 256, 0, stream>>>(src, dst, E, NB, cap, cntD, cntS, storeD, storeS);
    k_scan512<<<1, 512, 0, stream>>>(cntD, coarse, NB, rowptr + N, E);
    k_fin<<<NB, 256, 0, stream>>>(storeD, storeS, cntD, cntS, coarse, cap, N,
                                  rowptr, inv_in, inv_out, csr_src);

    // layer 1: Y1 = (x*inv_out)@W1 ; H = relu(gather(Y1)*inv_in + b1) * inv_out
    k_gemm2<D_HID><<<(N + BM - 1) / BM, 256, 0, stream>>>(x, W1, inv_out, Y1, N);
    k_gather<D_HID, true><<<(N + 3) / 4, 256, 0, stream>>>(rowptr, csr_src, Y1, inv_in, inv_out, b1, H, N);

    // layer 2: Y2 = H@W2 ; out = gather(Y2)*inv_in + b2
    k_gemm2<D_OUT><<<(N + BM - 1) / BM, 256, 0, stream>>>(H, W2, nullptr, Y2, N);
    k_gather<D_OUT, false><<<(N + 3) / 4, 256, 0, stream>>>(rowptr, csr_src, Y2, inv_in, nullptr, b2, out, N);
}

// Round 7
// 187.100 us; speedup vs baseline: 1.3387x; 1.3387x over previous
//
#include <hip/hip_runtime.h>

#define D_IN  128
#define D_HID 128
#define D_OUT 64
#define NBMAX 512      // max buckets (N <= 65536)
#define CHUNK 4096     // edges per k_bucket block
#define BM 128
#define BK 32

// ---------------------------------------------------------------- bucket scatter
// Counting-sort pass 1: scatter edges into 128-node dst-buckets (int2 src,dst)
// and src values into 128-node src-buckets. LDS-aggregated reservations.
__launch_bounds__(256)
__global__ void k_bucket(const int* __restrict__ src, const int* __restrict__ dst,
                         int E, int NB, int cap,
                         int* __restrict__ cntD, int* __restrict__ cntS,
                         int2* __restrict__ storeD, int* __restrict__ storeS) {
    __shared__ int lcD[NBMAX], lcS[NBMAX];
    __shared__ int lbD[NBMAX], lbS[NBMAX];
    const int t = threadIdx.x;
    const int e0 = blockIdx.x * CHUNK;
    const int e1 = min(e0 + CHUNK, E);

    for (int i = t; i < NB; i += 256) { lcD[i] = 0; lcS[i] = 0; }
    __syncthreads();
    for (int i = e0 + t; i < e1; i += 256) {
        atomicAdd(&lcD[dst[i] >> 7], 1);
        atomicAdd(&lcS[src[i] >> 7], 1);
    }
    __syncthreads();
    for (int i = t; i < NB; i += 256) {
        lbD[i] = lcD[i] ? atomicAdd(&cntD[i], lcD[i]) : 0;
        lbS[i] = lcS[i] ? atomicAdd(&cntS[i], lcS[i]) : 0;
        lcD[i] = 0; lcS[i] = 0;
    }
    __syncthreads();
    for (int i = e0 + t; i < e1; i += 256) {
        const int s = src[i], d = dst[i];
        const int bd = d >> 7;
        const int pd = lbD[bd] + atomicAdd(&lcD[bd], 1);
        storeD[(long long)bd * cap + pd] = make_int2(s, d);
        const int bs = s >> 7;
        const int ps = lbS[bs] + atomicAdd(&lcS[bs], 1);
        storeS[(long long)bs * cap + ps] = s;
    }
}

// ---------------------------------------------------------------- bucket scan
__launch_bounds__(512)
__global__ void k_scan512(const int* __restrict__ cntD, int* __restrict__ coarse_off,
                          int NB, int* __restrict__ rowptr_last, int E) {
    __shared__ int sh[512];
    const int t = threadIdx.x;
    const int v = (t < NB) ? cntD[t] : 0;
    sh[t] = v; __syncthreads();
    int inc = v;
    for (int off = 1; off < 512; off <<= 1) {
        int o = (t >= off) ? sh[t - off] : 0;
        __syncthreads();
        inc += o; sh[t] = inc;
        __syncthreads();
    }
    if (t < NB) coarse_off[t] = inc - v;
    if (t == 0) *rowptr_last = E;
}

// ---------------------------------------------------------------- finalize
// Per dst-bucket: 128-bin LDS histogram + scan -> rowptr, inv_in, csr_src.
// Then per src-bucket: histogram -> inv_out.
__launch_bounds__(256)
__global__ void k_fin(const int2* __restrict__ storeD, const int* __restrict__ storeS,
                      const int* __restrict__ cntD, const int* __restrict__ cntS,
                      const int* __restrict__ coarse_off, int cap, int N,
                      int* __restrict__ rowptr, float* __restrict__ inv_in,
                      float* __restrict__ inv_out, int* __restrict__ csr_src) {
    __shared__ int fh[128];
    __shared__ int sc[128];
    __shared__ int cur[128];
    const int b = blockIdx.x, t = threadIdx.x;
    const long long sb = (long long)b * cap;

    // ---- dst side: rowptr / inv_in / csr_src
    const int cnt  = cntD[b];
    const int base = coarse_off[b];
    if (t < 128) fh[t] = 0;
    __syncthreads();
    for (int i = t; i < cnt; i += 256) atomicAdd(&fh[storeD[sb + i].y & 127], 1);
    __syncthreads();
    if (t < 128) sc[t] = fh[t];
    __syncthreads();
    int inc = (t < 128) ? sc[t] : 0;
    for (int off = 1; off < 128; off <<= 1) {
        int o = (t >= off && t < 128) ? sc[t - off] : 0;
        __syncthreads();
        if (t < 128) { inc += o; sc[t] = inc; }
        __syncthreads();
    }
    if (t < 128) {
        const int excl = inc - fh[t];
        cur[t] = excl;
        const int node = (b << 7) + t;
        if (node < N) {
            rowptr[node] = base + excl;
            inv_in[node] = rsqrtf((float)max(fh[t], 1));
        }
    }
    __syncthreads();
    for (int i = t; i < cnt; i += 256) {
        const int2 e = storeD[sb + i];
        const int pos = atomicAdd(&cur[e.y & 127], 1);
        csr_src[base + pos] = e.x;
    }

    // ---- src side: inv_out
    __syncthreads();
    if (t < 128) fh[t] = 0;
    __syncthreads();
    const int cnts = cntS[b];
    for (int i = t; i < cnts; i += 256) atomicAdd(&fh[storeS[sb + i] & 127], 1);
    __syncthreads();
    if (t < 128) {
        const int node = (b << 7) + t;
        if (node < N) inv_out[node] = rsqrtf((float)max(fh[t], 1));
    }
}

// ---------------------------------------------------------------- register-blocked SGEMM
// Y[i][j] = sum_k X[i][k] * scale_i * W[k][j]   (scale optional)
// Block: 128 rows x 64 cols (col tile = blockIdx.y). 256 threads = 16x16,
// thread tile 8x4 (32 accs -> no spill risk). A staged transposed, stride 132
// (33*16B: float4-aligned). 3x ds_read_b128 per k feeding 32 FMAs.
template<int LDN>   // leading dimension of W and Y (128 or 64)
__launch_bounds__(256)
__global__ void k_gemm3(const float* __restrict__ X, const float* __restrict__ W,
                        const float* __restrict__ scale, float* __restrict__ Y, int N) {
    __shared__ float As[BK][BM + 4];
    __shared__ float Bs[BK][64];

    const int t  = threadIdx.x;
    const int tx = t & 15;
    const int ty = t >> 4;
    const int row0 = blockIdx.x * BM;
    const int col0 = blockIdx.y * 64;

    const int xr = t >> 3;                 // 0..31 (staging row within pass)
    const int xc = (t & 7) * 4;            // staging k-col

    float acc[8][4];
#pragma unroll
    for (int m = 0; m < 8; ++m)
#pragma unroll
        for (int n = 0; n < 4; ++n) acc[m][n] = 0.0f;

    for (int kk = 0; kk < D_IN; kk += BK) {
        __syncthreads();                   // protect previous-iteration reads
        // stage X tile (BM x BK) transposed, 4 passes of 32 rows
#pragma unroll
        for (int p = 0; p < 4; ++p) {
            const int r  = p * 32 + xr;
            const int gr = row0 + r;
            float4 v = make_float4(0.f, 0.f, 0.f, 0.f);
            if (gr < N) {
                v = *(const float4*)(X + (long long)gr * D_IN + kk + xc);
                if (scale) { const float s = scale[gr]; v.x *= s; v.y *= s; v.z *= s; v.w *= s; }
            }
            As[xc + 0][r] = v.x;
            As[xc + 1][r] = v.y;
            As[xc + 2][r] = v.z;
            As[xc + 3][r] = v.w;
        }
        // stage W tile (BK x 64): 512 float4, 2 per thread
#pragma unroll
        for (int p = 0; p < 2; ++p) {
            const int flat = p * 256 + t;          // float4 index, 0..511
            const int kr = flat >> 4;              // 16 float4 per row
            const int jc = (flat & 15) * 4;
            *(float4*)&Bs[kr][jc] = *(const float4*)(W + (long long)(kk + kr) * LDN + col0 + jc);
        }
        __syncthreads();

#pragma unroll
        for (int k = 0; k < BK; ++k) {
            const float4 a0 = *(const float4*)&As[k][ty * 8];
            const float4 a1 = *(const float4*)&As[k][ty * 8 + 4];
            const float4 b0 = *(const float4*)&Bs[k][tx * 4];
            const float am[8] = {a0.x, a0.y, a0.z, a0.w, a1.x, a1.y, a1.z, a1.w};
            const float bn[4] = {b0.x, b0.y, b0.z, b0.w};
#pragma unroll
            for (int m = 0; m < 8; ++m)
#pragma unroll
                for (int n = 0; n < 4; ++n)
                    acc[m][n] += am[m] * bn[n];
        }
    }

#pragma unroll
    for (int m = 0; m < 8; ++m) {
        const int gr = row0 + ty * 8 + m;
        if (gr < N)
            *(float4*)(Y + (long long)gr * LDN + col0 + tx * 4) =
                make_float4(acc[m][0], acc[m][1], acc[m][2], acc[m][3]);
    }
}

// ---------------------------------------------------------------- CSR gather
// One wave per destination node; EPW edges in flight (float4 per lane):
//   D=128: 2 edges x 32 lanes;  D=64: 4 edges x 16 lanes.
template<int D, bool RELU>
__launch_bounds__(256)
__global__ void k_gather(const int* __restrict__ rowptr, const int* __restrict__ csr_src,
                         const float* __restrict__ Y, const float* __restrict__ inv_in,
                         const float* __restrict__ inv_out, const float* __restrict__ b,
                         float* __restrict__ out, int N) {
    const int wid  = (int)((blockIdx.x * 256u + threadIdx.x) >> 6);
    const int lane = threadIdx.x & 63;
    if (wid >= N) return;

    const int start = rowptr[wid];
    const int end   = rowptr[wid + 1];

    constexpr int LPE = D / 4;            // lanes per edge (32 or 16)
    constexpr int EPW = 64 / LPE;         // edges in flight  (2 or 4)
    const int grp  = lane / LPE;          // 0..EPW-1
    const int col4 = (lane % LPE) * 4;

    float4 acc = make_float4(0.f, 0.f, 0.f, 0.f);
    for (int k = start; k < end; k += 64) {
        const int idx = k + lane;
        const int sv  = (idx < end) ? csr_src[idx] : 0;
        const int cnt = min(64, end - k);
        for (int j = 0; j < cnt; j += EPW) {
            const int jj = j + grp;
            const int s  = __shfl(sv, jj);
            if (jj < cnt) {
                float4 v = *(const float4*)(Y + (long long)s * D + col4);
                acc.x += v.x; acc.y += v.y; acc.z += v.z; acc.w += v.w;
            }
        }
    }

    // combine the EPW edge groups (they hold the same columns)
    acc.x += __shfl_down(acc.x, 32); acc.y += __shfl_down(acc.y, 32);
    acc.z += __shfl_down(acc.z, 32); acc.w += __shfl_down(acc.w, 32);
    if (EPW == 4) {
        acc.x += __shfl_down(acc.x, 16); acc.y += __shfl_down(acc.y, 16);
        acc.z += __shfl_down(acc.z, 16); acc.w += __shfl_down(acc.w, 16);
    }

    if (lane < LPE) {
        const float ii = inv_in[wid];
        const float4 bb = *(const float4*)(b + col4);
        float4 r;
        r.x = acc.x * ii + bb.x;
        r.y = acc.y * ii + bb.y;
        r.z = acc.z * ii + bb.z;
        r.w = acc.w * ii + bb.w;
        if (RELU) {
            const float io = inv_out[wid];
            r.x = fmaxf(r.x, 0.0f) * io;
            r.y = fmaxf(r.y, 0.0f) * io;
            r.z = fmaxf(r.z, 0.0f) * io;
            r.w = fmaxf(r.w, 0.0f) * io;
        }
        *(float4*)(out + (long long)wid * D + col4) = r;
    }
}

// ---------------------------------------------------------------- launch
extern "C" void kernel_launch(void* const* d_in, const int* in_sizes, int n_in,
                              void* d_out, int out_size, void* d_ws, size_t ws_size,
                              hipStream_t stream) {
    const int*   src = (const int*)d_in[0];
    const int*   dst = (const int*)d_in[1];
    const float* x   = (const float*)d_in[2];
    const float* W1  = (const float*)d_in[3];
    const float* b1  = (const float*)d_in[4];
    const float* W2  = (const float*)d_in[5];
    const float* b2  = (const float*)d_in[6];
    float* out = (float*)d_out;

    const int E  = in_sizes[0];
    const int N  = in_sizes[2] / D_IN;
    const int NB = (N + 127) >> 7;                 // 128-node buckets (<= NBMAX)
    const int mean = E / NB;
    const int cap  = mean + mean / 4 + 128;        // generous multinomial margin

    char* ws = (char*)d_ws;
    size_t off = 0;
    auto alloc = [&](size_t bytes) -> void* {
        void* p = ws + off;
        off += (bytes + 255) & ~(size_t)255;
        return p;
    };
    float* inv_out  = (float*)alloc((size_t)N * 4);
    float* inv_in   = (float*)alloc((size_t)N * 4);
    int*   rowptr   = (int*)alloc((size_t)(N + 1) * 4);
    int*   cntD     = (int*)alloc((size_t)NB * 4);
    int*   cntS     = (int*)alloc((size_t)NB * 4);
    int*   coarse   = (int*)alloc((size_t)NB * 4);
    int2*  storeD   = (int2*)alloc((size_t)NB * cap * 8);
    int*   storeS   = (int*)alloc((size_t)NB * cap * 4);
    int*   csr_src  = (int*)alloc((size_t)E * 4);
    float* Y1       = (float*)alloc((size_t)N * D_HID * 4);
    float* H        = (float*)alloc((size_t)N * D_HID * 4);
    float* Y2       = (float*)alloc((size_t)N * D_OUT * 4);
    (void)ws_size; (void)n_in; (void)out_size;

    hipMemsetAsync(cntD, 0, (size_t)NB * 4, stream);
    hipMemsetAsync(cntS, 0, (size_t)NB * 4, stream);

    // CSR build + degree norms (counting sort, LDS-aggregated)
    k_bucket<<<(E + CHUNK - 1) / CHUNK, 256, 0, stream>>>(src, dst, E, NB, cap, cntD, cntS, storeD, storeS);
    k_scan512<<<1, 512, 0, stream>>>(cntD, coarse, NB, rowptr + N, E);
    k_fin<<<NB, 256, 0, stream>>>(storeD, storeS, cntD, cntS, coarse, cap, N,
                                  rowptr, inv_in, inv_out, csr_src);

    // layer 1: Y1 = (x*inv_out)@W1 ; H = relu(gather(Y1)*inv_in + b1) * inv_out
    {
        dim3 g((N + BM - 1) / BM, D_HID / 64);
        k_gemm3<D_HID><<<g, 256, 0, stream>>>(x, W1, inv_out, Y1, N);
    }
    k_gather<D_HID, true><<<(N + 3) / 4, 256, 0, stream>>>(rowptr, csr_src, Y1, inv_in, inv_out, b1, H, N);

    // layer 2: Y2 = H@W2 ; out = gather(Y2)*inv_in + b2
    {
        dim3 g((N + BM - 1) / BM, D_OUT / 64);
        k_gemm3<D_OUT><<<g, 256, 0, stream>>>(H, W2, nullptr, Y2, N);
    }
    k_gather<D_OUT, false><<<(N + 3) / 4, 256, 0, stream>>>(rowptr, csr_src, Y2, inv_in, nullptr, b2, out, N);
}

// Round 8
// 153.948 us; speedup vs baseline: 1.6270x; 1.2153x over previous
//
#include <hip/hip_runtime.h>
#include <hip/hip_fp16.h>

#define D_IN  128
#define D_HID 128
#define D_OUT 64
#define NBMAX 512      // max buckets (N <= 65536; packed formats assume this)
#define CHUNK 2048     // edges per k_bucket block
#define BM 128
#define BK 32

// ---------------------------------------------------------------- bucket scatter
// Counting-sort pass 1: scatter edges into 128-node dst-buckets.
// storeD: packed uint = src | (dst&127)<<16   (needs N <= 65536)
// storeS: uchar = src&127 (for out-degree histogram)
__launch_bounds__(256)
__global__ void k_bucket(const int* __restrict__ src, const int* __restrict__ dst,
                         int E, int NB, int cap,
                         int* __restrict__ cntD, int* __restrict__ cntS,
                         unsigned int* __restrict__ storeD, unsigned char* __restrict__ storeS) {
    __shared__ int lcD[NBMAX], lcS[NBMAX];
    __shared__ int lbD[NBMAX], lbS[NBMAX];
    const int t = threadIdx.x;
    const int e0 = blockIdx.x * CHUNK;
    const int e1 = min(e0 + CHUNK, E);

    for (int i = t; i < NB; i += 256) { lcD[i] = 0; lcS[i] = 0; }
    __syncthreads();
    for (int i = e0 + t; i < e1; i += 256) {
        atomicAdd(&lcD[dst[i] >> 7], 1);
        atomicAdd(&lcS[src[i] >> 7], 1);
    }
    __syncthreads();
    for (int i = t; i < NB; i += 256) {
        lbD[i] = lcD[i] ? atomicAdd(&cntD[i], lcD[i]) : 0;
        lbS[i] = lcS[i] ? atomicAdd(&cntS[i], lcS[i]) : 0;
        lcD[i] = 0; lcS[i] = 0;
    }
    __syncthreads();
    for (int i = e0 + t; i < e1; i += 256) {
        const int s = src[i], d = dst[i];
        const int bd = d >> 7;
        const int pd = lbD[bd] + atomicAdd(&lcD[bd], 1);
        storeD[(long long)bd * cap + pd] = (unsigned int)s | ((unsigned int)(d & 127) << 16);
        const int bs = s >> 7;
        const int ps = lbS[bs] + atomicAdd(&lcS[bs], 1);
        storeS[(long long)bs * cap + ps] = (unsigned char)(s & 127);
    }
}

// ---------------------------------------------------------------- bucket scan
__launch_bounds__(512)
__global__ void k_scan512(const int* __restrict__ cntD, int* __restrict__ coarse_off,
                          int NB, int* __restrict__ rowptr_last, int E) {
    __shared__ int sh[512];
    const int t = threadIdx.x;
    const int v = (t < NB) ? cntD[t] : 0;
    sh[t] = v; __syncthreads();
    int inc = v;
    for (int off = 1; off < 512; off <<= 1) {
        int o = (t >= off) ? sh[t - off] : 0;
        __syncthreads();
        inc += o; sh[t] = inc;
        __syncthreads();
    }
    if (t < NB) coarse_off[t] = inc - v;
    if (t == 0) *rowptr_last = E;
}

// ---------------------------------------------------------------- finalize
// Per dst-bucket: 128-bin LDS histogram + scan -> rowptr, inv_in, csr_src (ushort).
// Then per src-bucket: histogram -> inv_out.
__launch_bounds__(256)
__global__ void k_fin(const unsigned int* __restrict__ storeD, const unsigned char* __restrict__ storeS,
                      const int* __restrict__ cntD, const int* __restrict__ cntS,
                      const int* __restrict__ coarse_off, int cap, int N,
                      int* __restrict__ rowptr, float* __restrict__ inv_in,
                      float* __restrict__ inv_out, unsigned short* __restrict__ csr_src) {
    __shared__ int fh[128];
    __shared__ int sc[128];
    __shared__ int cur[128];
    const int b = blockIdx.x, t = threadIdx.x;
    const long long sb = (long long)b * cap;

    // ---- dst side: rowptr / inv_in / csr_src
    const int cnt  = cntD[b];
    const int base = coarse_off[b];
    if (t < 128) fh[t] = 0;
    __syncthreads();
    for (int i = t; i < cnt; i += 256) atomicAdd(&fh[storeD[sb + i] >> 16], 1);
    __syncthreads();
    if (t < 128) sc[t] = fh[t];
    __syncthreads();
    int inc = (t < 128) ? sc[t] : 0;
    for (int off = 1; off < 128; off <<= 1) {
        int o = (t >= off && t < 128) ? sc[t - off] : 0;
        __syncthreads();
        if (t < 128) { inc += o; sc[t] = inc; }
        __syncthreads();
    }
    if (t < 128) {
        const int excl = inc - fh[t];
        cur[t] = excl;
        const int node = (b << 7) + t;
        if (node < N) {
            rowptr[node] = base + excl;
            inv_in[node] = rsqrtf((float)max(fh[t], 1));
        }
    }
    __syncthreads();
    for (int i = t; i < cnt; i += 256) {
        const unsigned int e = storeD[sb + i];
        const int pos = atomicAdd(&cur[e >> 16], 1);
        csr_src[base + pos] = (unsigned short)(e & 0xFFFFu);
    }

    // ---- src side: inv_out
    __syncthreads();
    if (t < 128) fh[t] = 0;
    __syncthreads();
    const int cnts = cntS[b];
    for (int i = t; i < cnts; i += 256) atomicAdd(&fh[storeS[sb + i]], 1);
    __syncthreads();
    if (t < 128) {
        const int node = (b << 7) + t;
        if (node < N) inv_out[node] = rsqrtf((float)max(fh[t], 1));
    }
}

// ---------------------------------------------------------------- register-blocked SGEMM, fp16 output
// Y[i][j] = (half) sum_k X[i][k] * scale_i * W[k][j]   (scale optional)
// Block: 128 rows x 64 cols (col tile = blockIdx.y). 256 threads = 16x16,
// thread tile 8x4. A staged transposed (stride 132, float4-aligned).
template<int LDN>   // leading dimension of W and Y (128 or 64)
__launch_bounds__(256)
__global__ void k_gemm3(const float* __restrict__ X, const float* __restrict__ W,
                        const float* __restrict__ scale, __half* __restrict__ Y, int N) {
    __shared__ float As[BK][BM + 4];
    __shared__ float Bs[BK][64];

    const int t  = threadIdx.x;
    const int tx = t & 15;
    const int ty = t >> 4;
    const int row0 = blockIdx.x * BM;
    const int col0 = blockIdx.y * 64;

    const int xr = t >> 3;                 // 0..31 (staging row within pass)
    const int xc = (t & 7) * 4;            // staging k-col

    float acc[8][4];
#pragma unroll
    for (int m = 0; m < 8; ++m)
#pragma unroll
        for (int n = 0; n < 4; ++n) acc[m][n] = 0.0f;

    for (int kk = 0; kk < D_IN; kk += BK) {
        __syncthreads();                   // protect previous-iteration reads
#pragma unroll
        for (int p = 0; p < 4; ++p) {
            const int r  = p * 32 + xr;
            const int gr = row0 + r;
            float4 v = make_float4(0.f, 0.f, 0.f, 0.f);
            if (gr < N) {
                v = *(const float4*)(X + (long long)gr * D_IN + kk + xc);
                if (scale) { const float s = scale[gr]; v.x *= s; v.y *= s; v.z *= s; v.w *= s; }
            }
            As[xc + 0][r] = v.x;
            As[xc + 1][r] = v.y;
            As[xc + 2][r] = v.z;
            As[xc + 3][r] = v.w;
        }
#pragma unroll
        for (int p = 0; p < 2; ++p) {
            const int flat = p * 256 + t;          // float4 index, 0..511
            const int kr = flat >> 4;              // 16 float4 per row
            const int jc = (flat & 15) * 4;
            *(float4*)&Bs[kr][jc] = *(const float4*)(W + (long long)(kk + kr) * LDN + col0 + jc);
        }
        __syncthreads();

#pragma unroll
        for (int k = 0; k < BK; ++k) {
            const float4 a0 = *(const float4*)&As[k][ty * 8];
            const float4 a1 = *(const float4*)&As[k][ty * 8 + 4];
            const float4 b0 = *(const float4*)&Bs[k][tx * 4];
            const float am[8] = {a0.x, a0.y, a0.z, a0.w, a1.x, a1.y, a1.z, a1.w};
            const float bn[4] = {b0.x, b0.y, b0.z, b0.w};
#pragma unroll
            for (int m = 0; m < 8; ++m)
#pragma unroll
                for (int n = 0; n < 4; ++n)
                    acc[m][n] += am[m] * bn[n];
        }
    }

#pragma unroll
    for (int m = 0; m < 8; ++m) {
        const int gr = row0 + ty * 8 + m;
        if (gr < N) {
            __half2 h0 = __float22half2_rn(make_float2(acc[m][0], acc[m][1]));
            __half2 h1 = __float22half2_rn(make_float2(acc[m][2], acc[m][3]));
            uint2 pk;
            pk.x = *(unsigned int*)&h0;
            pk.y = *(unsigned int*)&h1;
            *(uint2*)(Y + (long long)gr * LDN + col0 + tx * 4) = pk;
        }
    }
}

// ---------------------------------------------------------------- CSR gather (fp16 rows, fp32 accum)
// One wave per destination node; 8 halves (16B) per lane:
//   D=128: 16 lanes/edge x 4 edges in flight;  D=64: 8 lanes/edge x 8 in flight.
template<int D, bool RELU>
__launch_bounds__(256)
__global__ void k_gather(const int* __restrict__ rowptr, const unsigned short* __restrict__ csr_src,
                         const __half* __restrict__ Y, const float* __restrict__ inv_in,
                         const float* __restrict__ inv_out, const float* __restrict__ b,
                         float* __restrict__ out, int N) {
    const int wid  = (int)((blockIdx.x * 256u + threadIdx.x) >> 6);
    const int lane = threadIdx.x & 63;
    if (wid >= N) return;

    const int start = rowptr[wid];
    const int end   = rowptr[wid + 1];

    constexpr int LPE = D / 8;            // lanes per edge (16 or 8)
    constexpr int EPW = 64 / LPE;         // edges in flight (4 or 8)
    const int grp  = lane / LPE;          // 0..EPW-1
    const int colh = (lane % LPE) * 8;    // half index within row

    float a[8];
#pragma unroll
    for (int u = 0; u < 8; ++u) a[u] = 0.0f;

    for (int k = start; k < end; k += 64) {
        const int idx = k + lane;
        const int sv  = (idx < end) ? (int)csr_src[idx] : 0;
        const int cnt = min(64, end - k);
        for (int j = 0; j < cnt; j += EPW) {
            const int jj = j + grp;
            const int s  = __shfl(sv, jj);
            if (jj < cnt) {
                const uint4 raw = *(const uint4*)(Y + (long long)s * D + colh);
                const __half2* h = (const __half2*)&raw;
#pragma unroll
                for (int u = 0; u < 4; ++u) {
                    const float2 f = __half22float2(h[u]);
                    a[2 * u]     += f.x;
                    a[2 * u + 1] += f.y;
                }
            }
        }
    }

    // combine the EPW edge groups (they hold the same columns)
#pragma unroll
    for (int u = 0; u < 8; ++u) a[u] += __shfl_down(a[u], 32);
#pragma unroll
    for (int u = 0; u < 8; ++u) a[u] += __shfl_down(a[u], 16);
    if (EPW == 8) {
#pragma unroll
        for (int u = 0; u < 8; ++u) a[u] += __shfl_down(a[u], 8);
    }

    if (lane < LPE) {
        const float ii = inv_in[wid];
        const float io = RELU ? inv_out[wid] : 0.0f;
        const float4 b0 = *(const float4*)(b + colh);
        const float4 b1 = *(const float4*)(b + colh + 4);
        float r[8];
        r[0] = a[0] * ii + b0.x; r[1] = a[1] * ii + b0.y;
        r[2] = a[2] * ii + b0.z; r[3] = a[3] * ii + b0.w;
        r[4] = a[4] * ii + b1.x; r[5] = a[5] * ii + b1.y;
        r[6] = a[6] * ii + b1.z; r[7] = a[7] * ii + b1.w;
        if (RELU) {
#pragma unroll
            for (int u = 0; u < 8; ++u) r[u] = fmaxf(r[u], 0.0f) * io;
        }
        float* o = out + (long long)wid * D + colh;
        *(float4*)(o)     = make_float4(r[0], r[1], r[2], r[3]);
        *(float4*)(o + 4) = make_float4(r[4], r[5], r[6], r[7]);
    }
}

// ---------------------------------------------------------------- launch
extern "C" void kernel_launch(void* const* d_in, const int* in_sizes, int n_in,
                              void* d_out, int out_size, void* d_ws, size_t ws_size,
                              hipStream_t stream) {
    const int*   src = (const int*)d_in[0];
    const int*   dst = (const int*)d_in[1];
    const float* x   = (const float*)d_in[2];
    const float* W1  = (const float*)d_in[3];
    const float* b1  = (const float*)d_in[4];
    const float* W2  = (const float*)d_in[5];
    const float* b2  = (const float*)d_in[6];
    float* out = (float*)d_out;

    const int E  = in_sizes[0];
    const int N  = in_sizes[2] / D_IN;
    const int NB = (N + 127) >> 7;                 // 128-node buckets (<= NBMAX)
    const int mean = E / NB;
    const int cap  = mean + mean / 4 + 128;        // generous multinomial margin

    char* ws = (char*)d_ws;
    size_t off = 0;
    auto alloc = [&](size_t bytes) -> void* {
        void* p = ws + off;
        off += (bytes + 255) & ~(size_t)255;
        return p;
    };
    float*          inv_out = (float*)alloc((size_t)N * 4);
    float*          inv_in  = (float*)alloc((size_t)N * 4);
    int*            rowptr  = (int*)alloc((size_t)(N + 1) * 4);
    int*            cntD    = (int*)alloc((size_t)NB * 4);
    int*            cntS    = (int*)alloc((size_t)NB * 4);
    int*            coarse  = (int*)alloc((size_t)NB * 4);
    unsigned int*   storeD  = (unsigned int*)alloc((size_t)NB * cap * 4);
    unsigned char*  storeS  = (unsigned char*)alloc((size_t)NB * cap);
    unsigned short* csr_src = (unsigned short*)alloc((size_t)E * 2);
    __half*         Y1      = (__half*)alloc((size_t)N * D_HID * 2);
    float*          H       = (float*)alloc((size_t)N * D_HID * 4);
    __half*         Y2      = (__half*)alloc((size_t)N * D_OUT * 2);
    (void)ws_size; (void)n_in; (void)out_size;

    hipMemsetAsync(cntD, 0, (size_t)NB * 4, stream);
    hipMemsetAsync(cntS, 0, (size_t)NB * 4, stream);

    // CSR build + degree norms (counting sort, LDS-aggregated)
    k_bucket<<<(E + CHUNK - 1) / CHUNK, 256, 0, stream>>>(src, dst, E, NB, cap, cntD, cntS, storeD, storeS);
    k_scan512<<<1, 512, 0, stream>>>(cntD, coarse, NB, rowptr + N, E);
    k_fin<<<NB, 256, 0, stream>>>(storeD, storeS, cntD, cntS, coarse, cap, N,
                                  rowptr, inv_in, inv_out, csr_src);

    // layer 1: Y1 = (x*inv_out)@W1 ; H = relu(gather(Y1)*inv_in + b1) * inv_out
    {
        dim3 g((N + BM - 1) / BM, D_HID / 64);
        k_gemm3<D_HID><<<g, 256, 0, stream>>>(x, W1, inv_out, Y1, N);
    }
    k_gather<D_HID, true><<<(N + 3) / 4, 256, 0, stream>>>(rowptr, csr_src, Y1, inv_in, inv_out, b1, H, N);

    // layer 2: Y2 = H@W2 ; out = gather(Y2)*inv_in + b2
    {
        dim3 g((N + BM - 1) / BM, D_OUT / 64);
        k_gemm3<D_OUT><<<g, 256, 0, stream>>>(H, W2, nullptr, Y2, N);
    }
    k_gather<D_OUT, false><<<(N + 3) / 4, 256, 0, stream>>>(rowptr, csr_src, Y2, inv_in, nullptr, b2, out, N);
}

// Round 9
// 143.958 us; speedup vs baseline: 1.7399x; 1.0694x over previous
//
#include <hip/hip_runtime.h>
#include <hip/hip_fp16.h>

#define D_IN  128
#define D_HID 128
#define D_OUT 64
#define NBMAX 512      // max buckets (N <= 65536; packed formats assume this)
#define CHUNK 2048     // edges per k_bucket block
#define BM 128
#define BK 32
#define FCACHE 3072    // k_fin LDS edge cache (bucket mean ~2046, max ~2300)

// ---------------------------------------------------------------- zero counters
__global__ void k_zero(int* __restrict__ cntD, int* __restrict__ cntS, int NB) {
    const int t = threadIdx.x;
    if (t < NB) { cntD[t] = 0; cntS[t] = 0; }
}

// ---------------------------------------------------------------- bucket scatter
// Counting-sort pass 1: scatter edges into 128-node dst-buckets.
// storeD: packed uint = src | (dst&127)<<16   (needs N <= 65536)
// storeS: uchar = src&127 (for out-degree histogram)
__launch_bounds__(256)
__global__ void k_bucket(const int* __restrict__ src, const int* __restrict__ dst,
                         int E, int NB, int cap,
                         int* __restrict__ cntD, int* __restrict__ cntS,
                         unsigned int* __restrict__ storeD, unsigned char* __restrict__ storeS) {
    __shared__ int lcD[NBMAX], lcS[NBMAX];
    __shared__ int lbD[NBMAX], lbS[NBMAX];
    const int t = threadIdx.x;
    const int e0 = blockIdx.x * CHUNK;
    const int e1 = min(e0 + CHUNK, E);

    for (int i = t; i < NB; i += 256) { lcD[i] = 0; lcS[i] = 0; }
    __syncthreads();
    for (int i = e0 + t; i < e1; i += 256) {
        atomicAdd(&lcD[dst[i] >> 7], 1);
        atomicAdd(&lcS[src[i] >> 7], 1);
    }
    __syncthreads();
    for (int i = t; i < NB; i += 256) {
        lbD[i] = lcD[i] ? atomicAdd(&cntD[i], lcD[i]) : 0;
        lbS[i] = lcS[i] ? atomicAdd(&cntS[i], lcS[i]) : 0;
        lcD[i] = 0; lcS[i] = 0;
    }
    __syncthreads();
    for (int i = e0 + t; i < e1; i += 256) {
        const int s = src[i], d = dst[i];
        const int bd = d >> 7;
        const int pd = lbD[bd] + atomicAdd(&lcD[bd], 1);
        storeD[(long long)bd * cap + pd] = (unsigned int)s | ((unsigned int)(d & 127) << 16);
        const int bs = s >> 7;
        const int ps = lbS[bs] + atomicAdd(&lcS[bs], 1);
        storeS[(long long)bs * cap + ps] = (unsigned char)(s & 127);
    }
}

// ---------------------------------------------------------------- finalize (scan fused)
// Per dst-bucket: base = sum(cntD[0..b)), 128-bin LDS histogram + scan ->
// rowptr, inv_in, csr_src (ushort). Then per src-bucket: histogram -> inv_out.
__launch_bounds__(256)
__global__ void k_fin(const unsigned int* __restrict__ storeD, const unsigned char* __restrict__ storeS,
                      const int* __restrict__ cntD, const int* __restrict__ cntS,
                      int cap, int N, int NB, int E,
                      int* __restrict__ rowptr, float* __restrict__ inv_in,
                      float* __restrict__ inv_out, unsigned short* __restrict__ csr_src) {
    __shared__ int fh[128];
    __shared__ int sc[128];
    __shared__ int cur[128];
    __shared__ int red[256];
    __shared__ unsigned int ecache[FCACHE];
    const int b = blockIdx.x, t = threadIdx.x;
    const long long sb = (long long)b * cap;

    // ---- base = exclusive prefix of cntD at b (fused scan)
    int partial = 0;
    for (int i = t; i < b; i += 256) partial += cntD[i];
    red[t] = partial;
    __syncthreads();
    for (int off = 128; off > 0; off >>= 1) {
        if (t < off) red[t] += red[t + off];
        __syncthreads();
    }
    const int base = red[0];

    const int cnt = cntD[b];
    const bool cached = (cnt <= FCACHE);
    if (cached) {
        for (int i = t; i < cnt; i += 256) ecache[i] = storeD[sb + i];
    }

    // ---- dst side: rowptr / inv_in / csr_src
    if (t < 128) fh[t] = 0;
    __syncthreads();
    for (int i = t; i < cnt; i += 256) {
        const unsigned int e = cached ? ecache[i] : storeD[sb + i];
        atomicAdd(&fh[e >> 16], 1);
    }
    __syncthreads();
    if (t < 128) sc[t] = fh[t];
    __syncthreads();
    int inc = (t < 128) ? sc[t] : 0;
    for (int off = 1; off < 128; off <<= 1) {
        int o = (t >= off && t < 128) ? sc[t - off] : 0;
        __syncthreads();
        if (t < 128) { inc += o; sc[t] = inc; }
        __syncthreads();
    }
    if (t < 128) {
        const int excl = inc - fh[t];
        cur[t] = excl;
        const int node = (b << 7) + t;
        if (node < N) {
            rowptr[node] = base + excl;
            inv_in[node] = rsqrtf((float)max(fh[t], 1));
        }
    }
    if (b == NB - 1 && t == 128) rowptr[N] = E;
    __syncthreads();
    for (int i = t; i < cnt; i += 256) {
        const unsigned int e = cached ? ecache[i] : storeD[sb + i];
        const int pos = atomicAdd(&cur[e >> 16], 1);
        csr_src[base + pos] = (unsigned short)(e & 0xFFFFu);
    }

    // ---- src side: inv_out
    __syncthreads();
    if (t < 128) fh[t] = 0;
    __syncthreads();
    const int cnts = cntS[b];
    for (int i = t; i < cnts; i += 256) atomicAdd(&fh[storeS[sb + i]], 1);
    __syncthreads();
    if (t < 128) {
        const int node = (b << 7) + t;
        if (node < N) inv_out[node] = rsqrtf((float)max(fh[t], 1));
    }
}

// ---------------------------------------------------------------- register-blocked SGEMM, fp16 output
// Y[i][j] = (half) sum_k X[i][k] * scale_i * W[k][j]   (scale optional)
// Block: 128 rows x 64 cols (col tile = blockIdx.y). 256 threads = 16x16,
// thread tile 8x4. A staged transposed (stride 132, float4-aligned).
template<int LDN>   // leading dimension of W and Y (128 or 64)
__launch_bounds__(256)
__global__ void k_gemm3(const float* __restrict__ X, const float* __restrict__ W,
                        const float* __restrict__ scale, __half* __restrict__ Y, int N) {
    __shared__ float As[BK][BM + 4];
    __shared__ float Bs[BK][64];

    const int t  = threadIdx.x;
    const int tx = t & 15;
    const int ty = t >> 4;
    const int row0 = blockIdx.x * BM;
    const int col0 = blockIdx.y * 64;

    const int xr = t >> 3;                 // 0..31 (staging row within pass)
    const int xc = (t & 7) * 4;            // staging k-col

    float acc[8][4];
#pragma unroll
    for (int m = 0; m < 8; ++m)
#pragma unroll
        for (int n = 0; n < 4; ++n) acc[m][n] = 0.0f;

    for (int kk = 0; kk < D_IN; kk += BK) {
        __syncthreads();                   // protect previous-iteration reads
#pragma unroll
        for (int p = 0; p < 4; ++p) {
            const int r  = p * 32 + xr;
            const int gr = row0 + r;
            float4 v = make_float4(0.f, 0.f, 0.f, 0.f);
            if (gr < N) {
                v = *(const float4*)(X + (long long)gr * D_IN + kk + xc);
                if (scale) { const float s = scale[gr]; v.x *= s; v.y *= s; v.z *= s; v.w *= s; }
            }
            As[xc + 0][r] = v.x;
            As[xc + 1][r] = v.y;
            As[xc + 2][r] = v.z;
            As[xc + 3][r] = v.w;
        }
#pragma unroll
        for (int p = 0; p < 2; ++p) {
            const int flat = p * 256 + t;          // float4 index, 0..511
            const int kr = flat >> 4;              // 16 float4 per row
            const int jc = (flat & 15) * 4;
            *(float4*)&Bs[kr][jc] = *(const float4*)(W + (long long)(kk + kr) * LDN + col0 + jc);
        }
        __syncthreads();

#pragma unroll
        for (int k = 0; k < BK; ++k) {
            const float4 a0 = *(const float4*)&As[k][ty * 8];
            const float4 a1 = *(const float4*)&As[k][ty * 8 + 4];
            const float4 b0 = *(const float4*)&Bs[k][tx * 4];
            const float am[8] = {a0.x, a0.y, a0.z, a0.w, a1.x, a1.y, a1.z, a1.w};
            const float bn[4] = {b0.x, b0.y, b0.z, b0.w};
#pragma unroll
            for (int m = 0; m < 8; ++m)
#pragma unroll
                for (int n = 0; n < 4; ++n)
                    acc[m][n] += am[m] * bn[n];
        }
    }

#pragma unroll
    for (int m = 0; m < 8; ++m) {
        const int gr = row0 + ty * 8 + m;
        if (gr < N) {
            __half2 h0 = __float22half2_rn(make_float2(acc[m][0], acc[m][1]));
            __half2 h1 = __float22half2_rn(make_float2(acc[m][2], acc[m][3]));
            uint2 pk;
            pk.x = *(unsigned int*)&h0;
            pk.y = *(unsigned int*)&h1;
            *(uint2*)(Y + (long long)gr * LDN + col0 + tx * 4) = pk;
        }
    }
}

// ---------------------------------------------------------------- CSR gather (fp16 rows, fp32 accum)
// One wave per destination node; 8 halves (16B) per lane.
//   D=128: 16 lanes/edge x 4 edges/group;  D=64: 8 lanes/edge x 8 edges/group.
// Edge loop unrolled 4-deep: 4 independent uint4 loads in flight per lane.
template<int D, bool RELU>
__launch_bounds__(256)
__global__ void k_gather(const int* __restrict__ rowptr, const unsigned short* __restrict__ csr_src,
                         const __half* __restrict__ Y, const float* __restrict__ inv_in,
                         const float* __restrict__ inv_out, const float* __restrict__ b,
                         float* __restrict__ out, int N) {
    const int wid  = (int)((blockIdx.x * 256u + threadIdx.x) >> 6);
    const int lane = threadIdx.x & 63;
    if (wid >= N) return;

    const int start = rowptr[wid];
    const int end   = rowptr[wid + 1];

    constexpr int LPE = D / 8;            // lanes per edge (16 or 8)
    constexpr int EPW = 64 / LPE;         // edges per group (4 or 8)
    const int grp  = lane / LPE;          // 0..EPW-1
    const int colh = (lane % LPE) * 8;    // half index within row

    float a[8];
#pragma unroll
    for (int u = 0; u < 8; ++u) a[u] = 0.0f;

    auto accum = [&](uint4 raw) {
        const __half2* h = (const __half2*)&raw;
#pragma unroll
        for (int u = 0; u < 4; ++u) {
            const float2 f = __half22float2(h[u]);
            a[2 * u]     += f.x;
            a[2 * u + 1] += f.y;
        }
    };

    for (int k = start; k < end; k += 64) {
        const int idx = k + lane;
        const int sv  = (idx < end) ? (int)csr_src[idx] : 0;
        const int cnt = min(64, end - k);
        int j = 0;
        for (; j + 4 * EPW <= cnt; j += 4 * EPW) {
            const int s0 = __shfl(sv, j + grp);
            const int s1 = __shfl(sv, j + EPW + grp);
            const int s2 = __shfl(sv, j + 2 * EPW + grp);
            const int s3 = __shfl(sv, j + 3 * EPW + grp);
            const uint4 r0 = *(const uint4*)(Y + (long long)s0 * D + colh);
            const uint4 r1 = *(const uint4*)(Y + (long long)s1 * D + colh);
            const uint4 r2 = *(const uint4*)(Y + (long long)s2 * D + colh);
            const uint4 r3 = *(const uint4*)(Y + (long long)s3 * D + colh);
            accum(r0); accum(r1); accum(r2); accum(r3);
        }
        for (; j < cnt; j += EPW) {
            const int jj = j + grp;
            const int s  = __shfl(sv, jj);
            if (jj < cnt) {
                const uint4 r = *(const uint4*)(Y + (long long)s * D + colh);
                accum(r);
            }
        }
    }

    // combine the EPW edge groups (they hold the same columns)
#pragma unroll
    for (int u = 0; u < 8; ++u) a[u] += __shfl_down(a[u], 32);
#pragma unroll
    for (int u = 0; u < 8; ++u) a[u] += __shfl_down(a[u], 16);
    if (EPW == 8) {
#pragma unroll
        for (int u = 0; u < 8; ++u) a[u] += __shfl_down(a[u], 8);
    }

    if (lane < LPE) {
        const float ii = inv_in[wid];
        const float io = RELU ? inv_out[wid] : 0.0f;
        const float4 b0 = *(const float4*)(b + colh);
        const float4 b1 = *(const float4*)(b + colh + 4);
        float r[8];
        r[0] = a[0] * ii + b0.x; r[1] = a[1] * ii + b0.y;
        r[2] = a[2] * ii + b0.z; r[3] = a[3] * ii + b0.w;
        r[4] = a[4] * ii + b1.x; r[5] = a[5] * ii + b1.y;
        r[6] = a[6] * ii + b1.z; r[7] = a[7] * ii + b1.w;
        if (RELU) {
#pragma unroll
            for (int u = 0; u < 8; ++u) r[u] = fmaxf(r[u], 0.0f) * io;
        }
        float* o = out + (long long)wid * D + colh;
        *(float4*)(o)     = make_float4(r[0], r[1], r[2], r[3]);
        *(float4*)(o + 4) = make_float4(r[4], r[5], r[6], r[7]);
    }
}

// ---------------------------------------------------------------- launch
extern "C" void kernel_launch(void* const* d_in, const int* in_sizes, int n_in,
                              void* d_out, int out_size, void* d_ws, size_t ws_size,
                              hipStream_t stream) {
    const int*   src = (const int*)d_in[0];
    const int*   dst = (const int*)d_in[1];
    const float* x   = (const float*)d_in[2];
    const float* W1  = (const float*)d_in[3];
    const float* b1  = (const float*)d_in[4];
    const float* W2  = (const float*)d_in[5];
    const float* b2  = (const float*)d_in[6];
    float* out = (float*)d_out;

    const int E  = in_sizes[0];
    const int N  = in_sizes[2] / D_IN;
    const int NB = (N + 127) >> 7;                 // 128-node buckets (<= NBMAX)
    const int mean = E / NB;
    const int cap  = mean + mean / 4 + 128;        // generous multinomial margin

    char* ws = (char*)d_ws;
    size_t off = 0;
    auto alloc = [&](size_t bytes) -> void* {
        void* p = ws + off;
        off += (bytes + 255) & ~(size_t)255;
        return p;
    };
    float*          inv_out = (float*)alloc((size_t)N * 4);
    float*          inv_in  = (float*)alloc((size_t)N * 4);
    int*            rowptr  = (int*)alloc((size_t)(N + 1) * 4);
    int*            cntD    = (int*)alloc((size_t)NB * 4);
    int*            cntS    = (int*)alloc((size_t)NB * 4);
    unsigned int*   storeD  = (unsigned int*)alloc((size_t)NB * cap * 4);
    unsigned char*  storeS  = (unsigned char*)alloc((size_t)NB * cap);
    unsigned short* csr_src = (unsigned short*)alloc((size_t)E * 2);
    __half*         Y1      = (__half*)alloc((size_t)N * D_HID * 2);
    float*          H       = (float*)alloc((size_t)N * D_HID * 4);
    __half*         Y2      = (__half*)alloc((size_t)N * D_OUT * 2);
    (void)ws_size; (void)n_in; (void)out_size;

    // CSR build + degree norms (counting sort, LDS-aggregated; no memsets)
    k_zero<<<1, 512, 0, stream>>>(cntD, cntS, NB);
    k_bucket<<<(E + CHUNK - 1) / CHUNK, 256, 0, stream>>>(src, dst, E, NB, cap, cntD, cntS, storeD, storeS);
    k_fin<<<NB, 256, 0, stream>>>(storeD, storeS, cntD, cntS, cap, N, NB, E,
                                  rowptr, inv_in, inv_out, csr_src);

    // layer 1: Y1 = (x*inv_out)@W1 ; H = relu(gather(Y1)*inv_in + b1) * inv_out
    {
        dim3 g((N + BM - 1) / BM, D_HID / 64);
        k_gemm3<D_HID><<<g, 256, 0, stream>>>(x, W1, inv_out, Y1, N);
    }
    k_gather<D_HID, true><<<(N + 3) / 4, 256, 0, stream>>>(rowptr, csr_src, Y1, inv_in, inv_out, b1, H, N);

    // layer 2: Y2 = H@W2 ; out = gather(Y2)*inv_in + b2
    {
        dim3 g((N + BM - 1) / BM, D_OUT / 64);
        k_gemm3<D_OUT><<<g, 256, 0, stream>>>(H, W2, nullptr, Y2, N);
    }
    k_gather<D_OUT, false><<<(N + 3) / 4, 256, 0, stream>>>(rowptr, csr_src, Y2, inv_in, nullptr, b2, out, N);
}